// Round 1
// baseline (154.237 us; speedup 1.0000x reference)
//
#include <hip/hip_runtime.h>
#include <hip/hip_bf16.h>
#include <cstdint>

typedef __bf16 bf16x8 __attribute__((ext_vector_type(8)));
typedef float f32x4 __attribute__((ext_vector_type(4)));

__device__ __forceinline__ unsigned short f2b(float f) {
  __bf16 h = (__bf16)f;
  return __builtin_bit_cast(unsigned short, h);
}

__device__ __forceinline__ void gload_lds16(const void* g, void* l) {
  __builtin_amdgcn_global_load_lds(
      (__attribute__((address_space(1))) void*)g,
      (__attribute__((address_space(3))) void*)l,
      16, 0, 0);
}

// ---------------- fp32 -> bf16 elementwise convert ----------------
__global__ void cvt_f32_bf16(const float* __restrict__ in,
                             unsigned short* __restrict__ out, int n) {
  int i = (blockIdx.x * blockDim.x + threadIdx.x) * 4;
  if (i + 3 < n) {
    float4 f = *(const float4*)&in[i];
    ushort4 u = make_ushort4(f2b(f.x), f2b(f.y), f2b(f.z), f2b(f.w));
    *(ushort4*)&out[i] = u;
  }
}

// ---------------- fp32 [R][C] -> bf16 [C][R] transpose-convert ----------------
__global__ void transpose_cvt(const float* __restrict__ in,
                              unsigned short* __restrict__ out, int R, int C) {
  __shared__ float tile[32][33];
  int c0 = blockIdx.x * 32, r0 = blockIdx.y * 32;
  int x = threadIdx.x, y = threadIdx.y;
  #pragma unroll
  for (int j = y; j < 32; j += 8)
    tile[j][x] = in[(size_t)(r0 + j) * C + c0 + x];
  __syncthreads();
  #pragma unroll
  for (int j = y; j < 32; j += 8)
    out[(size_t)(c0 + j) * R + r0 + x] = f2b(tile[x][j]);
}

// ---------------- V transpose per head: qkv V-part -> Vt[bh][64][1024] ----------------
__global__ void transpose_v(const unsigned short* __restrict__ qkv,
                            unsigned short* __restrict__ vt) {
  __shared__ unsigned short tile[32][33];
  int bh = blockIdx.x, s0 = blockIdx.y * 32, d0 = blockIdx.z * 32;
  int b = bh >> 4, h = bh & 15;
  int x = threadIdx.x, y = threadIdx.y;
  #pragma unroll
  for (int j = y; j < 32; j += 8)
    tile[j][x] = qkv[(size_t)(b * 1024 + s0 + j) * 3072 + 2048 + h * 64 + d0 + x];
  __syncthreads();
  #pragma unroll
  for (int j = y; j < 32; j += 8)
    vt[(size_t)(bh * 64 + d0 + j) * 1024 + s0 + x] = tile[x][j];
}

// ---------------- bf16 GEMM, Bt input: C[M][N] = A[M][K] @ Bt[N][K]^T + bias ----------------
template <int OUT_F32>
__global__ __launch_bounds__(256, 2)
void gemm_bt(const unsigned short* __restrict__ A,
             const unsigned short* __restrict__ Bt,
             const float* __restrict__ bias, void* __restrict__ C,
             int M, int N, int K) {
  __shared__ __align__(16) unsigned short sA[128 * 32];
  __shared__ __align__(16) unsigned short sB[128 * 32];
  const int t = threadIdx.x;
  const int w = t >> 6, lane = t & 63;
  const int ln = lane & 15, lq = lane >> 4;
  const int wr = w >> 1, wc = w & 1;
  const int m0 = blockIdx.y * 128, n0 = blockIdx.x * 128;

  f32x4 acc[4][4];
  #pragma unroll
  for (int i = 0; i < 4; i++)
    #pragma unroll
    for (int j = 0; j < 4; j++) acc[i][j] = (f32x4){0.f, 0.f, 0.f, 0.f};

  for (int k0 = 0; k0 < K; k0 += 32) {
    __syncthreads();
    #pragma unroll
    for (int i = 0; i < 2; ++i) {
      int idx = i * 256 + t;
      int row = idx >> 2;        // 64B per row = 4 chunks of 16B
      int cb = (idx & 3) * 8;    // ushort offset
      gload_lds16(A + (size_t)(m0 + row) * K + k0 + cb, &sA[idx * 8]);
    }
    #pragma unroll
    for (int i = 0; i < 2; ++i) {
      int idx = i * 256 + t;
      int row = idx >> 2;
      int cb = (idx & 3) * 8;
      gload_lds16(Bt + (size_t)(n0 + row) * K + k0 + cb, &sB[idx * 8]);
    }
    __syncthreads();
    bf16x8 af[4], bfr[4];
    #pragma unroll
    for (int m = 0; m < 4; m++)
      af[m] = *(const bf16x8*)&sA[(wr * 64 + m * 16 + ln) * 32 + lq * 8];
    #pragma unroll
    for (int n = 0; n < 4; n++)
      bfr[n] = *(const bf16x8*)&sB[(wc * 64 + n * 16 + ln) * 32 + lq * 8];
    #pragma unroll
    for (int m = 0; m < 4; m++)
      #pragma unroll
      for (int n = 0; n < 4; n++)
        acc[m][n] = __builtin_amdgcn_mfma_f32_16x16x32_bf16(af[m], bfr[n], acc[m][n], 0, 0, 0);
  }

  #pragma unroll
  for (int m = 0; m < 4; m++) {
    #pragma unroll
    for (int n = 0; n < 4; n++) {
      int col = n0 + wc * 64 + n * 16 + ln;
      float bv = bias[col];
      #pragma unroll
      for (int r = 0; r < 4; r++) {
        int row = m0 + wr * 64 + m * 16 + lq * 4 + r;
        float v = acc[m][n][r] + bv;
        if (OUT_F32)
          ((float*)C)[(size_t)row * N + col] = v;
        else
          ((unsigned short*)C)[(size_t)row * N + col] = f2b(v);
      }
    }
  }
}

// ---------------- flash attention: Q[128-tile] x KV loop ----------------
__global__ __launch_bounds__(256, 2)
void attn_fwd(const unsigned short* __restrict__ qkv,
              const unsigned short* __restrict__ vt,
              unsigned short* __restrict__ aout) {
  const int b = blockIdx.z, h = blockIdx.y, q0 = blockIdx.x * 128;
  __shared__ __align__(16) unsigned short sQ[128 * 64];
  __shared__ __align__(16) unsigned short sK[64 * 64];
  __shared__ __align__(16) unsigned short sV[64 * 64];  // Vt tile [d][kv]
  __shared__ __align__(16) unsigned short sP[4][32 * 64];
  const int t = threadIdx.x;
  const int w = t >> 6, lane = t & 63;
  const int ln = lane & 15, lq = lane >> 4;
  const float SCALE = 0.125f;

  // stage Q [128][64]
  #pragma unroll
  for (int i = 0; i < 4; i++) {
    int idx = i * 256 + t;
    int row = idx >> 3, cb = (idx & 7) * 8;  // 128B rows = 8 chunks
    gload_lds16(qkv + (size_t)(b * 1024 + q0 + row) * 3072 + h * 64 + cb, &sQ[idx * 8]);
  }
  __syncthreads();
  bf16x8 qf[2][2];
  #pragma unroll
  for (int m = 0; m < 2; m++)
    #pragma unroll
    for (int c = 0; c < 2; c++)
      qf[m][c] = *(const bf16x8*)&sQ[(w * 32 + m * 16 + ln) * 64 + c * 32 + lq * 8];

  f32x4 o[2][4];
  float mrow[2][4], lsum[2][4];
  #pragma unroll
  for (int m = 0; m < 2; m++) {
    #pragma unroll
    for (int n = 0; n < 4; n++) o[m][n] = (f32x4){0.f, 0.f, 0.f, 0.f};
    #pragma unroll
    for (int r = 0; r < 4; r++) { mrow[m][r] = -1e30f; lsum[m][r] = 0.f; }
  }

  for (int kt = 0; kt < 16; ++kt) {
    const int kv0 = kt * 64;
    __syncthreads();
    #pragma unroll
    for (int i = 0; i < 2; i++) {
      int idx = i * 256 + t, row = idx >> 3, cb = (idx & 7) * 8;
      gload_lds16(qkv + (size_t)(b * 1024 + kv0 + row) * 3072 + 1024 + h * 64 + cb, &sK[idx * 8]);
    }
    #pragma unroll
    for (int i = 0; i < 2; i++) {
      int idx = i * 256 + t, row = idx >> 3, cb = (idx & 7) * 8;
      gload_lds16(vt + (size_t)((b * 16 + h) * 64 + row) * 1024 + kv0 + cb, &sV[idx * 8]);
    }
    __syncthreads();

    f32x4 s[2][4];
    #pragma unroll
    for (int m = 0; m < 2; m++)
      #pragma unroll
      for (int kc = 0; kc < 4; kc++) s[m][kc] = (f32x4){0.f, 0.f, 0.f, 0.f};
    #pragma unroll
    for (int kc = 0; kc < 4; kc++) {
      bf16x8 k0f = *(const bf16x8*)&sK[(kc * 16 + ln) * 64 + lq * 8];
      bf16x8 k1f = *(const bf16x8*)&sK[(kc * 16 + ln) * 64 + 32 + lq * 8];
      #pragma unroll
      for (int m = 0; m < 2; m++) {
        s[m][kc] = __builtin_amdgcn_mfma_f32_16x16x32_bf16(qf[m][0], k0f, s[m][kc], 0, 0, 0);
        s[m][kc] = __builtin_amdgcn_mfma_f32_16x16x32_bf16(qf[m][1], k1f, s[m][kc], 0, 0, 0);
      }
    }

    // online softmax (rows live at (lq*4+r); cols across 16 lanes x 4 kc-frags)
    #pragma unroll
    for (int m = 0; m < 2; m++) {
      #pragma unroll
      for (int r = 0; r < 4; r++) {
        float x0 = s[m][0][r] * SCALE, x1 = s[m][1][r] * SCALE;
        float x2 = s[m][2][r] * SCALE, x3 = s[m][3][r] * SCALE;
        float tm = fmaxf(fmaxf(x0, x1), fmaxf(x2, x3));
        tm = fmaxf(tm, __shfl_xor(tm, 1));
        tm = fmaxf(tm, __shfl_xor(tm, 2));
        tm = fmaxf(tm, __shfl_xor(tm, 4));
        tm = fmaxf(tm, __shfl_xor(tm, 8));
        float mo = mrow[m][r];
        float mn = fmaxf(mo, tm);
        float al = __expf(mo - mn);
        mrow[m][r] = mn;
        float p0 = __expf(x0 - mn), p1 = __expf(x1 - mn);
        float p2 = __expf(x2 - mn), p3 = __expf(x3 - mn);
        float ts = p0 + p1 + p2 + p3;
        ts += __shfl_xor(ts, 1);
        ts += __shfl_xor(ts, 2);
        ts += __shfl_xor(ts, 4);
        ts += __shfl_xor(ts, 8);
        lsum[m][r] = lsum[m][r] * al + ts;
        #pragma unroll
        for (int n = 0; n < 4; n++) o[m][n][r] *= al;
        unsigned short* pw = &sP[w][(m * 16 + lq * 4 + r) * 64 + ln];
        pw[0] = f2b(p0); pw[16] = f2b(p1); pw[32] = f2b(p2); pw[48] = f2b(p3);
      }
    }

    // PV: O += P @ V   (A = P rows q, k contiguous; B^T = Vt rows d)
    #pragma unroll
    for (int c2 = 0; c2 < 2; c2++) {
      bf16x8 pa0 = *(const bf16x8*)&sP[w][(0 + ln) * 64 + c2 * 32 + lq * 8];
      bf16x8 pa1 = *(const bf16x8*)&sP[w][(16 + ln) * 64 + c2 * 32 + lq * 8];
      #pragma unroll
      for (int n = 0; n < 4; n++) {
        bf16x8 vb = *(const bf16x8*)&sV[(n * 16 + ln) * 64 + c2 * 32 + lq * 8];
        o[0][n] = __builtin_amdgcn_mfma_f32_16x16x32_bf16(pa0, vb, o[0][n], 0, 0, 0);
        o[1][n] = __builtin_amdgcn_mfma_f32_16x16x32_bf16(pa1, vb, o[1][n], 0, 0, 0);
      }
    }
  }

  // epilogue: divide by l, store bf16
  #pragma unroll
  for (int m = 0; m < 2; m++) {
    float inv[4];
    #pragma unroll
    for (int r = 0; r < 4; r++) inv[r] = 1.f / lsum[m][r];
    #pragma unroll
    for (int n = 0; n < 4; n++) {
      #pragma unroll
      for (int r = 0; r < 4; r++) {
        int row = q0 + w * 32 + m * 16 + lq * 4 + r;
        int col = h * 64 + n * 16 + ln;
        aout[(size_t)(b * 1024 + row) * 1024 + col] = f2b(o[m][n][r] * inv[r]);
      }
    }
  }
}

extern "C" void kernel_launch(void* const* d_in, const int* in_sizes, int n_in,
                              void* d_out, int out_size, void* d_ws, size_t ws_size,
                              hipStream_t stream) {
  const float* x = (const float*)d_in[0];
  const float* W_qkv = (const float*)d_in[1];
  const float* b_qkv = (const float*)d_in[2];
  const float* W_out = (const float*)d_in[3];
  const float* b_out = (const float*)d_in[4];
  float* out = (float*)d_out;

  char* ws = (char*)d_ws;
  // layout (bytes): xb 8MB | WqkvT 6MB | WoutT 2MB | qkv 24MB | Vt 8MB | aout 8MB
  unsigned short* xb    = (unsigned short*)(ws);
  unsigned short* wqkvT = (unsigned short*)(ws + 8388608);
  unsigned short* woutT = (unsigned short*)(ws + 14680064);
  unsigned short* qkv   = (unsigned short*)(ws + 16777216);
  unsigned short* vt    = (unsigned short*)(ws + 41943040);
  unsigned short* aout  = (unsigned short*)(ws + 50331648);
  if (ws_size < 58720256) return;  // insufficient scratch -> loud failure

  cvt_f32_bf16<<<4096, 256, 0, stream>>>(x, xb, 4096 * 1024);
  transpose_cvt<<<dim3(96, 32), dim3(32, 8), 0, stream>>>(W_qkv, wqkvT, 1024, 3072);
  transpose_cvt<<<dim3(32, 32), dim3(32, 8), 0, stream>>>(W_out, woutT, 1024, 1024);
  gemm_bt<0><<<dim3(24, 32), 256, 0, stream>>>(xb, wqkvT, b_qkv, qkv, 4096, 3072, 1024);
  transpose_v<<<dim3(64, 32, 2), dim3(32, 8), 0, stream>>>(qkv, vt);
  attn_fwd<<<dim3(8, 16, 4), 256, 0, stream>>>(qkv, vt, aout);
  gemm_bt<1><<<dim3(8, 32), 256, 0, stream>>>(aout, woutT, b_out, out, 4096, 1024, 1024);
}

// Round 2
// 142.472 us; speedup vs baseline: 1.0826x; 1.0826x over previous
//
#include <hip/hip_runtime.h>
#include <hip/hip_bf16.h>
#include <cstdint>

typedef __bf16 bf16x8 __attribute__((ext_vector_type(8)));
typedef float f32x4 __attribute__((ext_vector_type(4)));

__device__ __forceinline__ unsigned short f2b(float f) {
  __bf16 h = (__bf16)f;
  return __builtin_bit_cast(unsigned short, h);
}

__device__ __forceinline__ void gload_lds16(const void* g, void* l) {
  __builtin_amdgcn_global_load_lds(
      (__attribute__((address_space(1))) void*)g,
      (__attribute__((address_space(3))) void*)l,
      16, 0, 0);
}

// ---------------- fp32 -> bf16 elementwise convert ----------------
__global__ void cvt_f32_bf16(const float* __restrict__ in,
                             unsigned short* __restrict__ out, int n) {
  int i = (blockIdx.x * blockDim.x + threadIdx.x) * 4;
  if (i + 3 < n) {
    float4 f = *(const float4*)&in[i];
    ushort4 u = make_ushort4(f2b(f.x), f2b(f.y), f2b(f.z), f2b(f.w));
    *(ushort4*)&out[i] = u;
  }
}

// ---------------- fp32 [R][C] -> bf16 [C][R] transpose-convert ----------------
__global__ void transpose_cvt(const float* __restrict__ in,
                              unsigned short* __restrict__ out, int R, int C) {
  __shared__ float tile[32][33];
  int c0 = blockIdx.x * 32, r0 = blockIdx.y * 32;
  int x = threadIdx.x, y = threadIdx.y;
  #pragma unroll
  for (int j = y; j < 32; j += 8)
    tile[j][x] = in[(size_t)(r0 + j) * C + c0 + x];
  __syncthreads();
  #pragma unroll
  for (int j = y; j < 32; j += 8)
    out[(size_t)(c0 + j) * R + r0 + x] = f2b(tile[x][j]);
}

// ---------------- V transpose per head: qkv V-part -> Vt[bh][64][1024] ----------------
__global__ void transpose_v(const unsigned short* __restrict__ qkv,
                            unsigned short* __restrict__ vt) {
  __shared__ unsigned short tile[32][33];
  int bh = blockIdx.x, s0 = blockIdx.y * 32, d0 = blockIdx.z * 32;
  int b = bh >> 4, h = bh & 15;
  int x = threadIdx.x, y = threadIdx.y;
  #pragma unroll
  for (int j = y; j < 32; j += 8)
    tile[j][x] = qkv[(size_t)(b * 1024 + s0 + j) * 3072 + 2048 + h * 64 + d0 + x];
  __syncthreads();
  #pragma unroll
  for (int j = y; j < 32; j += 8)
    vt[(size_t)(bh * 64 + d0 + j) * 1024 + s0 + x] = tile[x][j];
}

// ---------------- bf16 GEMM, Bt input: C[M][N] = A[M][K] @ Bt[N][K]^T + bias ----------------
template <int OUT_F32>
__global__ __launch_bounds__(256, 2)
void gemm_bt(const unsigned short* __restrict__ A,
             const unsigned short* __restrict__ Bt,
             const float* __restrict__ bias, void* __restrict__ C,
             int M, int N, int K) {
  __shared__ __align__(16) unsigned short sA[128 * 32];
  __shared__ __align__(16) unsigned short sB[128 * 32];
  const int t = threadIdx.x;
  const int w = t >> 6, lane = t & 63;
  const int ln = lane & 15, lq = lane >> 4;
  const int wr = w >> 1, wc = w & 1;
  const int m0 = blockIdx.y * 128, n0 = blockIdx.x * 128;

  f32x4 acc[4][4];
  #pragma unroll
  for (int i = 0; i < 4; i++)
    #pragma unroll
    for (int j = 0; j < 4; j++) acc[i][j] = (f32x4){0.f, 0.f, 0.f, 0.f};

  for (int k0 = 0; k0 < K; k0 += 32) {
    __syncthreads();
    #pragma unroll
    for (int i = 0; i < 2; ++i) {
      int idx = i * 256 + t;
      int row = idx >> 2;        // 64B per row = 4 chunks of 16B
      int cb = (idx & 3) * 8;    // ushort offset
      gload_lds16(A + (size_t)(m0 + row) * K + k0 + cb, &sA[idx * 8]);
    }
    #pragma unroll
    for (int i = 0; i < 2; ++i) {
      int idx = i * 256 + t;
      int row = idx >> 2;
      int cb = (idx & 3) * 8;
      gload_lds16(Bt + (size_t)(n0 + row) * K + k0 + cb, &sB[idx * 8]);
    }
    __syncthreads();
    bf16x8 af[4], bfr[4];
    #pragma unroll
    for (int m = 0; m < 4; m++)
      af[m] = *(const bf16x8*)&sA[(wr * 64 + m * 16 + ln) * 32 + lq * 8];
    #pragma unroll
    for (int n = 0; n < 4; n++)
      bfr[n] = *(const bf16x8*)&sB[(wc * 64 + n * 16 + ln) * 32 + lq * 8];
    #pragma unroll
    for (int m = 0; m < 4; m++)
      #pragma unroll
      for (int n = 0; n < 4; n++)
        acc[m][n] = __builtin_amdgcn_mfma_f32_16x16x32_bf16(af[m], bfr[n], acc[m][n], 0, 0, 0);
  }

  #pragma unroll
  for (int m = 0; m < 4; m++) {
    #pragma unroll
    for (int n = 0; n < 4; n++) {
      int col = n0 + wc * 64 + n * 16 + ln;
      float bv = bias[col];
      #pragma unroll
      for (int r = 0; r < 4; r++) {
        int row = m0 + wr * 64 + m * 16 + lq * 4 + r;
        float v = acc[m][n][r] + bv;
        if (OUT_F32)
          ((float*)C)[(size_t)row * N + col] = v;
        else
          ((unsigned short*)C)[(size_t)row * N + col] = f2b(v);
      }
    }
  }
}

// ---------------- flash attention: Q[64-tile] x KV loop, XOR-swizzled LDS ----------------
// LDS layout rule: logical element (row, col[ushort]) of a [R][64] tile lives at
// byte  row*128 + ((col*2) ^ ((row&7)<<4)).  Staging via global_load_lds writes
// LDS linearly, so the global SOURCE chunk is pre-swizzled: ch_src = ch ^ (row&7).
__global__ __launch_bounds__(256, 4)
void attn_fwd(const unsigned short* __restrict__ qkv,
              const unsigned short* __restrict__ vt,
              unsigned short* __restrict__ aout) {
  const int b = blockIdx.z, h = blockIdx.y, q0 = blockIdx.x * 64;
  __shared__ __align__(16) unsigned short sQ[64 * 64];
  __shared__ __align__(16) unsigned short sK[64 * 64];
  __shared__ __align__(16) unsigned short sV[64 * 64];  // Vt tile [d][kv]
  __shared__ __align__(16) unsigned short sP[4][16 * 64];
  const int t = threadIdx.x;
  const int w = t >> 6, lane = t & 63;
  const int ln = lane & 15, lq = lane >> 4;
  const float SCALE = 0.125f;

  // stage Q [64][64], source pre-swizzled
  #pragma unroll
  for (int i = 0; i < 2; i++) {
    int idx = i * 256 + t;
    int row = idx >> 3, ch = idx & 7;
    gload_lds16(qkv + (size_t)(b * 1024 + q0 + row) * 3072 + h * 64 + ((ch ^ (row & 7)) * 8),
                &sQ[idx * 8]);
  }
  __syncthreads();
  bf16x8 qf[2];
  #pragma unroll
  for (int c = 0; c < 2; c++) {
    int row = w * 16 + ln;
    qf[c] = *(const bf16x8*)&sQ[row * 64 + ((c * 4 + lq) ^ (ln & 7)) * 8];
  }

  f32x4 o[4];
  float mrow[4], lsum[4];
  #pragma unroll
  for (int n = 0; n < 4; n++) o[n] = (f32x4){0.f, 0.f, 0.f, 0.f};
  #pragma unroll
  for (int r = 0; r < 4; r++) { mrow[r] = -1e30f; lsum[r] = 0.f; }

  for (int kt = 0; kt < 16; ++kt) {
    const int kv0 = kt * 64;
    __syncthreads();
    #pragma unroll
    for (int i = 0; i < 2; i++) {
      int idx = i * 256 + t, row = idx >> 3, ch = idx & 7;
      gload_lds16(qkv + (size_t)(b * 1024 + kv0 + row) * 3072 + 1024 + h * 64 + ((ch ^ (row & 7)) * 8),
                  &sK[idx * 8]);
    }
    #pragma unroll
    for (int i = 0; i < 2; i++) {
      int idx = i * 256 + t, row = idx >> 3, ch = idx & 7;
      gload_lds16(vt + (size_t)((b * 16 + h) * 64 + row) * 1024 + kv0 + ((ch ^ (row & 7)) * 8),
                  &sV[idx * 8]);
    }
    __syncthreads();

    // QK^T: S[16 q][64 k] per wave
    f32x4 s[4];
    #pragma unroll
    for (int kc = 0; kc < 4; kc++) s[kc] = (f32x4){0.f, 0.f, 0.f, 0.f};
    #pragma unroll
    for (int kc = 0; kc < 4; kc++) {
      int krow = kc * 16 + ln;
      bf16x8 k0f = *(const bf16x8*)&sK[krow * 64 + ((0 + lq) ^ (ln & 7)) * 8];
      bf16x8 k1f = *(const bf16x8*)&sK[krow * 64 + ((4 + lq) ^ (ln & 7)) * 8];
      s[kc] = __builtin_amdgcn_mfma_f32_16x16x32_bf16(qf[0], k0f, s[kc], 0, 0, 0);
      s[kc] = __builtin_amdgcn_mfma_f32_16x16x32_bf16(qf[1], k1f, s[kc], 0, 0, 0);
    }

    // online softmax (rows at lq*4+r; cols across 16 lanes x 4 kc-frags)
    unsigned char* pb = (unsigned char*)sP[w];
    #pragma unroll
    for (int r = 0; r < 4; r++) {
      float x0 = s[0][r] * SCALE, x1 = s[1][r] * SCALE;
      float x2 = s[2][r] * SCALE, x3 = s[3][r] * SCALE;
      float tm = fmaxf(fmaxf(x0, x1), fmaxf(x2, x3));
      tm = fmaxf(tm, __shfl_xor(tm, 1));
      tm = fmaxf(tm, __shfl_xor(tm, 2));
      tm = fmaxf(tm, __shfl_xor(tm, 4));
      tm = fmaxf(tm, __shfl_xor(tm, 8));
      float mo = mrow[r];
      float mn = fmaxf(mo, tm);
      float al = __expf(mo - mn);
      mrow[r] = mn;
      float p0 = __expf(x0 - mn), p1 = __expf(x1 - mn);
      float p2 = __expf(x2 - mn), p3 = __expf(x3 - mn);
      float ts = p0 + p1 + p2 + p3;
      ts += __shfl_xor(ts, 1);
      ts += __shfl_xor(ts, 2);
      ts += __shfl_xor(ts, 4);
      ts += __shfl_xor(ts, 8);
      lsum[r] = lsum[r] * al + ts;
      #pragma unroll
      for (int n = 0; n < 4; n++) o[n][r] *= al;
      int row = lq * 4 + r;
      int sw = (row & 7) << 4;
      int base = row * 128 + ln * 2;
      *(unsigned short*)(pb + ((base + 0) ^ sw)) = f2b(p0);
      *(unsigned short*)(pb + ((base + 32) ^ sw)) = f2b(p1);
      *(unsigned short*)(pb + ((base + 64) ^ sw)) = f2b(p2);
      *(unsigned short*)(pb + ((base + 96) ^ sw)) = f2b(p3);
    }

    // PV: O += P @ V   (A = P[16 q][64 k]; B^T = Vt rows d)
    #pragma unroll
    for (int c2 = 0; c2 < 2; c2++) {
      bf16x8 pa = *(const bf16x8*)&sP[w][ln * 64 + ((c2 * 4 + lq) ^ (ln & 7)) * 8];
      #pragma unroll
      for (int n = 0; n < 4; n++) {
        int vrow = n * 16 + ln;
        bf16x8 vb = *(const bf16x8*)&sV[vrow * 64 + ((c2 * 4 + lq) ^ (ln & 7)) * 8];
        o[n] = __builtin_amdgcn_mfma_f32_16x16x32_bf16(pa, vb, o[n], 0, 0, 0);
      }
    }
  }

  // epilogue: divide by l, store bf16
  float inv[4];
  #pragma unroll
  for (int r = 0; r < 4; r++) inv[r] = 1.f / lsum[r];
  #pragma unroll
  for (int n = 0; n < 4; n++) {
    #pragma unroll
    for (int r = 0; r < 4; r++) {
      int row = q0 + w * 16 + lq * 4 + r;
      int col = h * 64 + n * 16 + ln;
      aout[(size_t)(b * 1024 + row) * 1024 + col] = f2b(o[n][r] * inv[r]);
    }
  }
}

extern "C" void kernel_launch(void* const* d_in, const int* in_sizes, int n_in,
                              void* d_out, int out_size, void* d_ws, size_t ws_size,
                              hipStream_t stream) {
  const float* x = (const float*)d_in[0];
  const float* W_qkv = (const float*)d_in[1];
  const float* b_qkv = (const float*)d_in[2];
  const float* W_out = (const float*)d_in[3];
  const float* b_out = (const float*)d_in[4];
  float* out = (float*)d_out;

  char* ws = (char*)d_ws;
  // layout (bytes): xb 8MB | WqkvT 6MB | WoutT 2MB | qkv 24MB | Vt 8MB | aout 8MB
  unsigned short* xb    = (unsigned short*)(ws);
  unsigned short* wqkvT = (unsigned short*)(ws + 8388608);
  unsigned short* woutT = (unsigned short*)(ws + 14680064);
  unsigned short* qkv   = (unsigned short*)(ws + 16777216);
  unsigned short* vt    = (unsigned short*)(ws + 41943040);
  unsigned short* aout  = (unsigned short*)(ws + 50331648);
  if (ws_size < 58720256) return;  // insufficient scratch -> loud failure

  cvt_f32_bf16<<<4096, 256, 0, stream>>>(x, xb, 4096 * 1024);
  transpose_cvt<<<dim3(96, 32), dim3(32, 8), 0, stream>>>(W_qkv, wqkvT, 1024, 3072);
  transpose_cvt<<<dim3(32, 32), dim3(32, 8), 0, stream>>>(W_out, woutT, 1024, 1024);
  gemm_bt<0><<<dim3(24, 32), 256, 0, stream>>>(xb, wqkvT, b_qkv, qkv, 4096, 3072, 1024);
  transpose_v<<<dim3(64, 32, 2), dim3(32, 8), 0, stream>>>(qkv, vt);
  attn_fwd<<<dim3(16, 16, 4), 256, 0, stream>>>(qkv, vt, aout);
  gemm_bt<1><<<dim3(8, 32), 256, 0, stream>>>(aout, woutT, b_out, out, 4096, 1024, 1024);
}

// Round 3
// 125.172 us; speedup vs baseline: 1.2322x; 1.1382x over previous
//
#include <hip/hip_runtime.h>
#include <hip/hip_bf16.h>
#include <cstdint>

typedef __bf16 bf16x8 __attribute__((ext_vector_type(8)));
typedef float f32x4 __attribute__((ext_vector_type(4)));

__device__ __forceinline__ unsigned short f2b(float f) {
  __bf16 h = (__bf16)f;
  return __builtin_bit_cast(unsigned short, h);
}

__device__ __forceinline__ void gload_lds16(const void* g, void* l) {
  __builtin_amdgcn_global_load_lds(
      (__attribute__((address_space(1))) void*)g,
      (__attribute__((address_space(3))) void*)l,
      16, 0, 0);
}

// ---------------- fp32 -> bf16 elementwise convert ----------------
__global__ void cvt_f32_bf16(const float* __restrict__ in,
                             unsigned short* __restrict__ out, int n) {
  int i = (blockIdx.x * blockDim.x + threadIdx.x) * 4;
  if (i + 3 < n) {
    float4 f = *(const float4*)&in[i];
    ushort4 u = make_ushort4(f2b(f.x), f2b(f.y), f2b(f.z), f2b(f.w));
    *(ushort4*)&out[i] = u;
  }
}

// ---------------- fp32 [R][C] -> bf16 [C][R] transpose-convert ----------------
__global__ void transpose_cvt(const float* __restrict__ in,
                              unsigned short* __restrict__ out, int R, int C) {
  __shared__ float tile[32][33];
  int c0 = blockIdx.x * 32, r0 = blockIdx.y * 32;
  int x = threadIdx.x, y = threadIdx.y;
  #pragma unroll
  for (int j = y; j < 32; j += 8)
    tile[j][x] = in[(size_t)(r0 + j) * C + c0 + x];
  __syncthreads();
  #pragma unroll
  for (int j = y; j < 32; j += 8)
    out[(size_t)(c0 + j) * R + r0 + x] = f2b(tile[x][j]);
}

// ---------------- V transpose per head: qkv V-part -> Vt[bh][64][1024] ----------------
__global__ void transpose_v(const unsigned short* __restrict__ qkv,
                            unsigned short* __restrict__ vt) {
  __shared__ unsigned short tile[32][33];
  int bh = blockIdx.x, s0 = blockIdx.y * 32, d0 = blockIdx.z * 32;
  int b = bh >> 4, h = bh & 15;
  int x = threadIdx.x, y = threadIdx.y;
  #pragma unroll
  for (int j = y; j < 32; j += 8)
    tile[j][x] = qkv[(size_t)(b * 1024 + s0 + j) * 3072 + 2048 + h * 64 + d0 + x];
  __syncthreads();
  #pragma unroll
  for (int j = y; j < 32; j += 8)
    vt[(size_t)(bh * 64 + d0 + j) * 1024 + s0 + x] = tile[x][j];
}

// ---------------- bf16 GEMM, Bt input: C[M][N] = A[M][K] @ Bt[N][K]^T + bias ----------------
template <int OUT_F32>
__global__ __launch_bounds__(256, 2)
void gemm_bt(const unsigned short* __restrict__ A,
             const unsigned short* __restrict__ Bt,
             const float* __restrict__ bias, void* __restrict__ C,
             int M, int N, int K) {
  __shared__ __align__(16) unsigned short sA[128 * 32];
  __shared__ __align__(16) unsigned short sB[128 * 32];
  const int t = threadIdx.x;
  const int w = t >> 6, lane = t & 63;
  const int ln = lane & 15, lq = lane >> 4;
  const int wr = w >> 1, wc = w & 1;
  const int m0 = blockIdx.y * 128, n0 = blockIdx.x * 128;

  f32x4 acc[4][4];
  #pragma unroll
  for (int i = 0; i < 4; i++)
    #pragma unroll
    for (int j = 0; j < 4; j++) acc[i][j] = (f32x4){0.f, 0.f, 0.f, 0.f};

  for (int k0 = 0; k0 < K; k0 += 32) {
    __syncthreads();
    #pragma unroll
    for (int i = 0; i < 2; ++i) {
      int idx = i * 256 + t;
      int row = idx >> 2;        // 64B per row = 4 chunks of 16B
      int cb = (idx & 3) * 8;    // ushort offset
      gload_lds16(A + (size_t)(m0 + row) * K + k0 + cb, &sA[idx * 8]);
    }
    #pragma unroll
    for (int i = 0; i < 2; ++i) {
      int idx = i * 256 + t;
      int row = idx >> 2;
      int cb = (idx & 3) * 8;
      gload_lds16(Bt + (size_t)(n0 + row) * K + k0 + cb, &sB[idx * 8]);
    }
    __syncthreads();
    bf16x8 af[4], bfr[4];
    #pragma unroll
    for (int m = 0; m < 4; m++)
      af[m] = *(const bf16x8*)&sA[(wr * 64 + m * 16 + ln) * 32 + lq * 8];
    #pragma unroll
    for (int n = 0; n < 4; n++)
      bfr[n] = *(const bf16x8*)&sB[(wc * 64 + n * 16 + ln) * 32 + lq * 8];
    #pragma unroll
    for (int m = 0; m < 4; m++)
      #pragma unroll
      for (int n = 0; n < 4; n++)
        acc[m][n] = __builtin_amdgcn_mfma_f32_16x16x32_bf16(af[m], bfr[n], acc[m][n], 0, 0, 0);
  }

  #pragma unroll
  for (int m = 0; m < 4; m++) {
    #pragma unroll
    for (int n = 0; n < 4; n++) {
      int col = n0 + wc * 64 + n * 16 + ln;
      float bv = bias[col];
      #pragma unroll
      for (int r = 0; r < 4; r++) {
        int row = m0 + wr * 64 + m * 16 + lq * 4 + r;
        float v = acc[m][n][r] + bv;
        if (OUT_F32)
          ((float*)C)[(size_t)row * N + col] = v;
        else
          ((unsigned short*)C)[(size_t)row * N + col] = f2b(v);
      }
    }
  }
}

// ---------------- flash attention ----------------
// Swapped QK^T: S^T = mfma(K_frag, Q_frag) puts q on the lane axis (q = ln),
// k in-register (16 values/lane) -> softmax k-reduce is in-lane + 2 shfl.
// LDS: 4 x 8KB buffers (Q stage reused as V-odd) + per-wave P = 40 KB.
// XOR swizzle rule: (row, col) of a [R][64] ushort tile at byte
//   row*128 + ((col*2) ^ ((row&7)<<4));  gload_lds source pre-swizzled.
__global__ __launch_bounds__(256, 4)
void attn_fwd(const unsigned short* __restrict__ qkv,
              const unsigned short* __restrict__ vt,
              unsigned short* __restrict__ aout) {
  const int b = blockIdx.z, h = blockIdx.y, q0 = blockIdx.x * 64;
  __shared__ __align__(16) unsigned short sB[4][64 * 64];
  __shared__ __align__(16) unsigned short sP[4][16 * 64];
  const int t = threadIdx.x;
  const int w = t >> 6, lane = t & 63;
  const int ln = lane & 15, lq = lane >> 4;
  const float SCALE = 0.125f;

  const size_t qbase = (size_t)(b * 1024 + q0) * 3072 + h * 64;
  const size_t kbase = (size_t)(b * 1024) * 3072 + 1024 + h * 64;
  const size_t vbase = (size_t)((b * 16 + h) * 64) * 1024;

  // prologue: stage Q -> sB[0], K0 -> sB[1], V0 -> sB[2]
  #pragma unroll
  for (int i = 0; i < 2; i++) {
    int idx = i * 256 + t;
    int row = idx >> 3, ch = idx & 7;
    int sw = (ch ^ (row & 7)) * 8;
    gload_lds16(qkv + qbase + (size_t)row * 3072 + sw, &sB[0][idx * 8]);
    gload_lds16(qkv + kbase + (size_t)row * 3072 + sw, &sB[1][idx * 8]);
    gload_lds16(vt + vbase + (size_t)row * 1024 + sw, &sB[2][idx * 8]);
  }
  __syncthreads();
  bf16x8 qf[2];
  #pragma unroll
  for (int c = 0; c < 2; c++) {
    int row = w * 16 + ln;
    qf[c] = *(const bf16x8*)&sB[0][row * 64 + ((c * 4 + lq) ^ (ln & 7)) * 8];
  }
  __syncthreads();  // qf reads done before sB[0] is reused for V-odd

  f32x4 o[4];
  float mrow = -1e30f, lsum = 0.f;
  #pragma unroll
  for (int n = 0; n < 4; n++) o[n] = (f32x4){0.f, 0.f, 0.f, 0.f};

  for (int kt = 0; kt < 16; ++kt) {
    const unsigned short* kb = sB[(kt & 1) ? 3 : 1];
    const unsigned short* vb = sB[(kt & 1) ? 0 : 2];
    if (kt < 15) {
      const int kv1 = (kt + 1) * 64;
      unsigned short* kn = sB[(kt & 1) ? 1 : 3];
      unsigned short* vn = sB[(kt & 1) ? 2 : 0];
      #pragma unroll
      for (int i = 0; i < 2; i++) {
        int idx = i * 256 + t;
        int row = idx >> 3, ch = idx & 7;
        int sw = (ch ^ (row & 7)) * 8;
        gload_lds16(qkv + kbase + (size_t)(kv1 + row) * 3072 + sw, &kn[idx * 8]);
        gload_lds16(vt + vbase + (size_t)row * 1024 + kv1 + sw, &vn[idx * 8]);
      }
    }

    // QK^T swapped: st[kc] = S^T block, lane holds q=ln, k = kc*16 + lq*4 + reg
    f32x4 st[4];
    #pragma unroll
    for (int kc = 0; kc < 4; kc++) st[kc] = (f32x4){0.f, 0.f, 0.f, 0.f};
    #pragma unroll
    for (int kc = 0; kc < 4; kc++) {
      int krow = kc * 16 + ln;
      bf16x8 k0f = *(const bf16x8*)&kb[krow * 64 + ((0 + lq) ^ (ln & 7)) * 8];
      bf16x8 k1f = *(const bf16x8*)&kb[krow * 64 + ((4 + lq) ^ (ln & 7)) * 8];
      st[kc] = __builtin_amdgcn_mfma_f32_16x16x32_bf16(k0f, qf[0], st[kc], 0, 0, 0);
      st[kc] = __builtin_amdgcn_mfma_f32_16x16x32_bf16(k1f, qf[1], st[kc], 0, 0, 0);
    }

    // softmax over k (in-lane 16 values + 2 shfl)
    float xv[4][4];
    float tm = -1e30f;
    #pragma unroll
    for (int kc = 0; kc < 4; kc++) {
      #pragma unroll
      for (int r = 0; r < 4; r++) {
        xv[kc][r] = st[kc][r] * SCALE;
        tm = fmaxf(tm, xv[kc][r]);
      }
    }
    tm = fmaxf(tm, __shfl_xor(tm, 16));
    tm = fmaxf(tm, __shfl_xor(tm, 32));
    float mn = fmaxf(mrow, tm);
    float al = __expf(mrow - mn);
    mrow = mn;
    float ts = 0.f;
    #pragma unroll
    for (int kc = 0; kc < 4; kc++) {
      #pragma unroll
      for (int r = 0; r < 4; r++) {
        xv[kc][r] = __expf(xv[kc][r] - mn);
        ts += xv[kc][r];
      }
    }
    ts += __shfl_xor(ts, 16);
    ts += __shfl_xor(ts, 32);
    lsum = lsum * al + ts;

    // rescale O (O rows are q = lq*4 + r; al lives on lane with ln == q)
    #pragma unroll
    for (int r = 0; r < 4; r++) {
      float alr = __shfl(al, (lane & 48) | (lq * 4 + r));
      #pragma unroll
      for (int n = 0; n < 4; n++) o[n][r] *= alr;
    }

    // P -> LDS: lane writes 4 bf16 (k = kc*16 + lq*4 .. +3) for row q = ln
    unsigned char* pb = (unsigned char*)sP[w];
    #pragma unroll
    for (int kc = 0; kc < 4; kc++) {
      ushort4 u = make_ushort4(f2b(xv[kc][0]), f2b(xv[kc][1]),
                               f2b(xv[kc][2]), f2b(xv[kc][3]));
      int boff = (kc * 32 + lq * 8) ^ ((ln & 7) << 4);
      *(ushort4*)(pb + ln * 128 + boff) = u;
    }

    // PV: O += P @ V  (A = P[16 q][64 k]; B^T = Vt rows dv)
    #pragma unroll
    for (int c2 = 0; c2 < 2; c2++) {
      bf16x8 pa = *(const bf16x8*)&sP[w][ln * 64 + ((c2 * 4 + lq) ^ (ln & 7)) * 8];
      #pragma unroll
      for (int n = 0; n < 4; n++) {
        int vrow = n * 16 + ln;
        bf16x8 vf = *(const bf16x8*)&vb[vrow * 64 + ((c2 * 4 + lq) ^ (ln & 7)) * 8];
        o[n] = __builtin_amdgcn_mfma_f32_16x16x32_bf16(pa, vf, o[n], 0, 0, 0);
      }
    }

    asm volatile("s_waitcnt vmcnt(0)" ::: "memory");
    __builtin_amdgcn_s_barrier();
  }

  // epilogue: divide by l (lsum lives on lane ln == q-row), store bf16
  float linv[4];
  #pragma unroll
  for (int r = 0; r < 4; r++)
    linv[r] = 1.f / __shfl(lsum, (lane & 48) | (lq * 4 + r));
  #pragma unroll
  for (int n = 0; n < 4; n++) {
    #pragma unroll
    for (int r = 0; r < 4; r++) {
      int row = q0 + w * 16 + lq * 4 + r;
      int col = h * 64 + n * 16 + ln;
      aout[(size_t)(b * 1024 + row) * 1024 + col] = f2b(o[n][r] * linv[r]);
    }
  }
}

extern "C" void kernel_launch(void* const* d_in, const int* in_sizes, int n_in,
                              void* d_out, int out_size, void* d_ws, size_t ws_size,
                              hipStream_t stream) {
  const float* x = (const float*)d_in[0];
  const float* W_qkv = (const float*)d_in[1];
  const float* b_qkv = (const float*)d_in[2];
  const float* W_out = (const float*)d_in[3];
  const float* b_out = (const float*)d_in[4];
  float* out = (float*)d_out;

  char* ws = (char*)d_ws;
  // layout (bytes): xb 8MB | WqkvT 6MB | WoutT 2MB | qkv 24MB | Vt 8MB | aout 8MB
  unsigned short* xb    = (unsigned short*)(ws);
  unsigned short* wqkvT = (unsigned short*)(ws + 8388608);
  unsigned short* woutT = (unsigned short*)(ws + 14680064);
  unsigned short* qkv   = (unsigned short*)(ws + 16777216);
  unsigned short* vt    = (unsigned short*)(ws + 41943040);
  unsigned short* aout  = (unsigned short*)(ws + 50331648);
  if (ws_size < 58720256) return;  // insufficient scratch -> loud failure

  cvt_f32_bf16<<<4096, 256, 0, stream>>>(x, xb, 4096 * 1024);
  transpose_cvt<<<dim3(96, 32), dim3(32, 8), 0, stream>>>(W_qkv, wqkvT, 1024, 3072);
  transpose_cvt<<<dim3(32, 32), dim3(32, 8), 0, stream>>>(W_out, woutT, 1024, 1024);
  gemm_bt<0><<<dim3(24, 32), 256, 0, stream>>>(xb, wqkvT, b_qkv, qkv, 4096, 3072, 1024);
  transpose_v<<<dim3(64, 32, 2), dim3(32, 8), 0, stream>>>(qkv, vt);
  attn_fwd<<<dim3(16, 16, 4), 256, 0, stream>>>(qkv, vt, aout);
  gemm_bt<1><<<dim3(8, 32), 256, 0, stream>>>(aout, woutT, b_out, out, 4096, 1024, 1024);
}